// Round 8
// baseline (449.235 us; speedup 1.0000x reference)
//
#include <hip/hip_runtime.h>
#include <hip/hip_fp16.h>
#include <math.h>

#define N_NODES 50000
#define N_EDGES 1600000
#define D_IN 128
#define D_H 64
#define N_CLS 10
#define N_GRAPHS 64
#define NEG_SLOPE 0.2f
#define E2 (N_EDGES + N_NODES)   // edges + self loops
#define SCAN_BS 256
#define NBLK ((N_NODES + SCAN_BS - 1) / SCAN_BS)   // 196 <= 256

// bucketed scatter params
#define NB 25                 // buckets: dst >> 11 (50000/2048 -> 0..24)
#define BSH 11
#define CAP 76800             // per-bucket staging capacity (>40 sigma over E/NB)
#define HBB 8                 // hist blocks per bucket
#define EPT 8                 // edges/thread in bucket_stage
#define PAD 32                // 128B stride: one cache line per contended counter
#define SLICES 8              // node-slices per bucket in scatter_slice
#define SLICE_W (2048 / SLICES)   // 256 nodes per slice

// packed fp16 via clang ext_vector — plain operators lower to v_pk_*_f16.
// (r5 lesson: ROCm 7.2 hip_fp16.h has NO __hmax2/__hmul2 half2 intrinsics.)
typedef _Float16 f16x2 __attribute__((ext_vector_type(2)));

__device__ inline f16x2 as_h2(unsigned u) { return __builtin_bit_cast(f16x2, u); }
__device__ inline int h2_as_int(f16x2 v) { return __builtin_bit_cast(int, v); }

__device__ inline f16x2 pk_leaky(f16x2 m, f16x2 ns) {
#if __has_builtin(__builtin_elementwise_max)
    return __builtin_elementwise_max(m, m * ns);
#else
    f16x2 p = m * ns, r;
    r.x = m.x > p.x ? m.x : p.x;
    r.y = m.y > p.y ? m.y : p.y;
    return r;
#endif
}

#if __has_builtin(__builtin_amdgcn_fdot2)
__device__ inline float fdot2a(f16x2 a, f16x2 b, float c) {
    return __builtin_amdgcn_fdot2(a, b, c, false);
}
#else
__device__ inline float fdot2a(f16x2 a, f16x2 b, float c) {
    return fmaf((float)a.x, (float)b.x, fmaf((float)a.y, (float)b.y, c));
}
#endif

__device__ inline float wave_reduce_sum(float v) {
    for (int off = 32; off; off >>= 1) v += __shfl_xor(v, off);
    return v;
}

// ===== pass A: bucket-stage edges + eattr sum.
// r0 fix (verified): contended-line atomics were the serializer. esum spread
// over 32 lines, bcursor one line per bucket, EPT=8, int2 staging.
// r4: eattr staged as half2(a,a) so gat's hot loop needs no per-edge cvt.
__global__ void bucket_stage(const int* __restrict__ src, const int* __restrict__ dst,
                             const float* __restrict__ eattr,
                             float* esum, int* bcursor,
                             int2* __restrict__ stg) {
    __shared__ int bcnt[4][32];
    __shared__ int woff[4][32];
    __shared__ float esh[4];
    int t = threadIdx.x;
    int wave = t >> 6;
    if (t < 128) bcnt[t >> 5][t & 31] = 0;
    __syncthreads();
    int e0 = (blockIdx.x * blockDim.x + t) * EPT;   // N_EDGES % EPT == 0
    int ss[EPT], tt[EPT], aa[EPT], r[EPT], b[EPT];
    float v = 0.f;
    bool valid = e0 < N_EDGES;
    if (valid) {
        #pragma unroll
        for (int q = 0; q < EPT / 4; ++q) {
            int4 s4 = *(const int4*)(src + e0 + 4 * q);
            int4 t4 = *(const int4*)(dst + e0 + 4 * q);
            float4 a4 = *(const float4*)(eattr + e0 + 4 * q);
            ss[4*q] = s4.x; ss[4*q+1] = s4.y; ss[4*q+2] = s4.z; ss[4*q+3] = s4.w;
            tt[4*q] = t4.x; tt[4*q+1] = t4.y; tt[4*q+2] = t4.z; tt[4*q+3] = t4.w;
            aa[4*q]   = h2_as_int((f16x2){(_Float16)a4.x, (_Float16)a4.x});
            aa[4*q+1] = h2_as_int((f16x2){(_Float16)a4.y, (_Float16)a4.y});
            aa[4*q+2] = h2_as_int((f16x2){(_Float16)a4.z, (_Float16)a4.z});
            aa[4*q+3] = h2_as_int((f16x2){(_Float16)a4.w, (_Float16)a4.w});
            v += (a4.x + a4.y) + (a4.z + a4.w);
        }
        #pragma unroll
        for (int i = 0; i < EPT; ++i) {
            b[i] = tt[i] >> BSH;
            r[i] = atomicAdd(&bcnt[wave][b[i]], 1);
        }
    }
    v = wave_reduce_sum(v);
    if ((t & 63) == 0) esh[wave] = v;
    __syncthreads();
    if (t < NB) {
        int c0 = bcnt[0][t], c1 = bcnt[1][t], c2 = bcnt[2][t], c3 = bcnt[3][t];
        int tot = c0 + c1 + c2 + c3;
        int base = tot ? atomicAdd(&bcursor[t * PAD], tot) : 0;
        woff[0][t] = base;
        woff[1][t] = base + c0;
        woff[2][t] = base + c0 + c1;
        woff[3][t] = base + c0 + c1 + c2;
    }
    if (t == 0) {
        float tot = (esh[0] + esh[1]) + (esh[2] + esh[3]);
        atomicAdd(&esum[(blockIdx.x & 31) * PAD], tot);   // 32 distinct lines
    }
    __syncthreads();
    if (valid) {
        #pragma unroll
        for (int i = 0; i < EPT; ++i) {
            int p = b[i] * CAP + woff[wave][b[i]] + r[i];
            stg[p] = make_int2((ss[i] & 0xFFFF) | ((tt[i] & 2047) << 16), aa[i]);
        }
    }
}

// ===== pass A2: per-node histogram from staged dst-low bits, LDS-resident window
__global__ void hist_bucket(const int2* __restrict__ stg, const int* __restrict__ bcursor,
                            int* cnt) {
    __shared__ int hist[2048];
    int b = blockIdx.x / HBB;
    int j = blockIdx.x % HBB;
    for (int i = threadIdx.x; i < 2048; i += 256) hist[i] = 0;
    __syncthreads();
    int n = bcursor[b * PAD];
    const int2* sd = stg + (size_t)b * CAP;
    int per = (n + HBB - 1) / HBB;
    int start = j * per;
    int end = min(start + per, n);
    for (int idx = start + threadIdx.x; idx < end; idx += 256)
        atomicAdd(&hist[(sd[idx].x >> 16) & 2047], 1);
    __syncthreads();
    int nb = b << BSH;
    for (int i = threadIdx.x; i < 2048; i += 256) {
        int c = hist[i];
        if (c) atomicAdd(&cnt[nb + i], c);
    }
}

// ---- block-local exclusive scan; +1 per node folds in the self-loop slot ----
__global__ void scan_block(const int* __restrict__ cnt, int* __restrict__ row_start,
                           int* __restrict__ partial) {
    __shared__ int sd[SCAN_BS];
    int i = blockIdx.x * SCAN_BS + threadIdx.x;
    int v = (i < N_NODES) ? (cnt[i] + 1) : 0;   // +1 = self loop
    sd[threadIdx.x] = v;
    __syncthreads();
    for (int off = 1; off < SCAN_BS; off <<= 1) {
        int t = (threadIdx.x >= off) ? sd[threadIdx.x - off] : 0;
        __syncthreads();
        sd[threadIdx.x] += t;
        __syncthreads();
    }
    if (i < N_NODES) row_start[i] = sd[threadIdx.x] - v;
    if (threadIdx.x == SCAN_BS - 1) partial[blockIdx.x] = sd[threadIdx.x];
}
// finalize row_start (redundant LDS scan of partials replaces a launch),
// write self-loop CSR entry (eattr-mean as half2), seed cursor
__global__ void add_offsets(int* __restrict__ row_start, const int* __restrict__ partial,
                            int* __restrict__ cursor, const float* __restrict__ esum,
                            int2* __restrict__ csr_pack) {
    __shared__ int sp[SCAN_BS];
    int pv = (threadIdx.x < NBLK) ? partial[threadIdx.x] : 0;
    sp[threadIdx.x] = pv;
    __syncthreads();
    for (int off = 1; off < SCAN_BS; off <<= 1) {
        int t = (threadIdx.x >= off) ? sp[threadIdx.x - off] : 0;
        __syncthreads();
        sp[threadIdx.x] += t;
        __syncthreads();
    }
    float es = 0.f;
    #pragma unroll
    for (int jj = 0; jj < 32; ++jj) es += esum[jj * PAD];
    float esm = es * (1.0f / N_EDGES);
    int ebits = h2_as_int((f16x2){(_Float16)esm, (_Float16)esm});
    int base = (blockIdx.x == 0) ? 0 : sp[blockIdx.x - 1];
    int i = blockIdx.x * SCAN_BS + threadIdx.x;
    if (i < N_NODES) {
        int r = row_start[i] + base;
        row_start[i] = r;
        csr_pack[r] = make_int2(i, ebits);
        cursor[i] = r + 1;
    }
    if (i == 0) row_start[N_NODES] = E2;
}

// ===== pass B (r3-verified): slice-owned scatter, LDS cursors, deep MLP.
__global__ __launch_bounds__(1024) void scatter_slice(
                              const int2* __restrict__ stg,
                              const int* __restrict__ bcursor,
                              const int* __restrict__ row_start,
                              int2* __restrict__ csr_pack) {
    __shared__ int lcur[SLICE_W];
    int b = blockIdx.x & 31;
    int m = blockIdx.x >> 5;
    if (b >= NB) return;
    int nbase = (b << BSH) + m * SLICE_W;
    for (int i = threadIdx.x; i < SLICE_W; i += 1024) {
        int node = nbase + i;
        lcur[i] = (node < N_NODES) ? row_start[node] + 1 : 0;  // +1 skips self-loop slot
    }
    __syncthreads();
    int n = bcursor[b * PAD];
    const int4* sd4 = (const int4*)(stg + (size_t)b * CAP);   // b*CAP*8B is 16B-aligned
    int n4 = n >> 1;
    int lo = m * SLICE_W, hi = lo + SLICE_W;
    for (int base4 = 0; base4 < n4; base4 += 4096) {
        int4 e[4];
        int idx[4];
        #pragma unroll
        for (int j = 0; j < 4; ++j) {
            idx[j] = base4 + j * 1024 + (int)threadIdx.x;
            if (idx[j] < n4) e[j] = sd4[idx[j]];
        }
        #pragma unroll
        for (int j = 0; j < 4; ++j) {
            if (idx[j] < n4) {
                int dl0 = (e[j].x >> 16) & 2047;
                if (dl0 >= lo && dl0 < hi) {
                    int q = atomicAdd(&lcur[dl0 - lo], 1);
                    csr_pack[q] = make_int2(e[j].x & 0xFFFF, e[j].y);
                }
                int dl1 = (e[j].z >> 16) & 2047;
                if (dl1 >= lo && dl1 < hi) {
                    int q = atomicAdd(&lcur[dl1 - lo], 1);
                    csr_pack[q] = make_int2(e[j].z & 0xFFFF, e[j].w);
                }
            }
        }
    }
    if ((n & 1) && threadIdx.x == 0) {   // odd tail edge; only owning slice stores
        int2 e = stg[(size_t)b * CAP + n - 1];
        int dl = (e.x >> 16) & 2047;
        if (dl >= lo && dl < hi) {
            int q = atomicAdd(&lcur[dl - lo], 1);
            csr_pack[q] = make_int2(e.x & 0xFFFF, e.y);
        }
    }
}

// ---- xl = x@Wl + bl ; xr = x@Wr + br -> fp16 outputs.
// r7 rewrite: r1's LDS version was co-limited by wave-BROADCAST ds_read_b128
// (16B useful per ~12cy LDS slot, 64-way redundant; VGPR=44 shows the
// compiler collapsed the unroll into a serialized load-use chain; VALUBusy
// 38%, 49us vs 10.4us FMA floor). New decomposition: 64 lanes = 8 nodes x
// 8 dims; each lane streams its node's x row from GLOBAL (float4/k4, 8
// distinct 128B lines per instr, L1-reused across 8 iters) and coalesced
// weight rows (L1/L2-resident). No LDS, no barriers.
template<int K>
__global__ __launch_bounds__(256) void linear_dual_k(
                              const float* __restrict__ x,
                              const float* __restrict__ Wl, const float* __restrict__ bl,
                              const float* __restrict__ Wr, const float* __restrict__ br,
                              __half* __restrict__ xl, __half* __restrict__ xr) {
    int lane = threadIdx.x & 63;
    int wave = threadIdx.x >> 6;
    int dg = (lane & 7) * 8;                       // dim-group base (8 dims/lane)
    int node = blockIdx.x * 32 + wave * 8 + (lane >> 3);
    bool nv = node < N_NODES;
    const float* xrow = x + (size_t)(nv ? node : 0) * K;
    float al[8], ar[8];
    #pragma unroll
    for (int j = 0; j < 8; ++j) { al[j] = bl[dg + j]; ar[j] = br[dg + j]; }
    for (int k4 = 0; k4 < K / 4; ++k4) {
        int kb = k4 * 4;
        float4 xv = *(const float4*)(xrow + kb);
        float xq[4] = {xv.x, xv.y, xv.z, xv.w};
        #pragma unroll
        for (int q = 0; q < 4; ++q) {
            float4 wla = *(const float4*)(Wl + (kb + q) * D_H + dg);
            float4 wlb = *(const float4*)(Wl + (kb + q) * D_H + dg + 4);
            float4 wra = *(const float4*)(Wr + (kb + q) * D_H + dg);
            float4 wrb = *(const float4*)(Wr + (kb + q) * D_H + dg + 4);
            al[0] = fmaf(xq[q], wla.x, al[0]);
            al[1] = fmaf(xq[q], wla.y, al[1]);
            al[2] = fmaf(xq[q], wla.z, al[2]);
            al[3] = fmaf(xq[q], wla.w, al[3]);
            al[4] = fmaf(xq[q], wlb.x, al[4]);
            al[5] = fmaf(xq[q], wlb.y, al[5]);
            al[6] = fmaf(xq[q], wlb.z, al[6]);
            al[7] = fmaf(xq[q], wlb.w, al[7]);
            ar[0] = fmaf(xq[q], wra.x, ar[0]);
            ar[1] = fmaf(xq[q], wra.y, ar[1]);
            ar[2] = fmaf(xq[q], wra.z, ar[2]);
            ar[3] = fmaf(xq[q], wra.w, ar[3]);
            ar[4] = fmaf(xq[q], wrb.x, ar[4]);
            ar[5] = fmaf(xq[q], wrb.y, ar[5]);
            ar[6] = fmaf(xq[q], wrb.z, ar[6]);
            ar[7] = fmaf(xq[q], wrb.w, ar[7]);
        }
    }
    if (nv) {
        int4 pl = make_int4(
            h2_as_int((f16x2){(_Float16)al[0], (_Float16)al[1]}),
            h2_as_int((f16x2){(_Float16)al[2], (_Float16)al[3]}),
            h2_as_int((f16x2){(_Float16)al[4], (_Float16)al[5]}),
            h2_as_int((f16x2){(_Float16)al[6], (_Float16)al[7]}));
        int4 pr = make_int4(
            h2_as_int((f16x2){(_Float16)ar[0], (_Float16)ar[1]}),
            h2_as_int((f16x2){(_Float16)ar[2], (_Float16)ar[3]}),
            h2_as_int((f16x2){(_Float16)ar[4], (_Float16)ar[5]}),
            h2_as_int((f16x2){(_Float16)ar[6], (_Float16)ar[7]}));
        *(int4*)(xl + (size_t)node * D_H + dg) = pl;   // 16B aligned (dg*2 % 16 == 0)
        *(int4*)(xr + (size_t)node * D_H + dg) = pr;
    }
}

// ---- fused GATv2 layer — r6-verified design; r7: 8 edges/iter for gather MLP.
// r6 counters: VALUBusy 60% (packed-fp16 cut verified), 40% stall on the
// csr_pack->xl two-level gather with only 4 loads in flight. 8/iter doubles
// MLP; +~6% padded slots is the trade. VGPR ~70, occupancy unaffected.
__global__ __launch_bounds__(256) void gat_fused(
        const int* __restrict__ row_start, const int2* __restrict__ csr_pack,
        const __half* __restrict__ xl, const __half* __restrict__ xr,
        const float* __restrict__ We, const float* __restrict__ att,
        const float* __restrict__ b, float* __restrict__ out) {
    int lane = threadIdx.x & 63;
    int g = lane >> 4;
    int s = lane & 15;
    int wid = blockIdx.x * (blockDim.x >> 6) + (threadIdx.x >> 6);
    int node = wid * 4 + g;                 // 16 nodes per 256-thread block
    bool nv = node < N_NODES;
    int nodec = nv ? node : 0;
    int fb = s * 4;
    float4 we4  = *(const float4*)(We + fb);
    float4 att4 = *(const float4*)(att + fb);
    f16x2 we0 = {(_Float16)we4.x, (_Float16)we4.y};
    f16x2 we1 = {(_Float16)we4.z, (_Float16)we4.w};
    f16x2 at0 = {(_Float16)att4.x, (_Float16)att4.y};
    f16x2 at1 = {(_Float16)att4.z, (_Float16)att4.w};
    uint2 xru = *(const uint2*)(xr + (size_t)nodec * D_H + fb);
    f16x2 xr0 = as_h2(xru.x), xr1 = as_h2(xru.y);
    const f16x2 ns = {(_Float16)NEG_SLOPE, (_Float16)NEG_SLOPE};
    int j0 = 0, j1 = 0;
    if (nv) { j0 = row_start[node]; j1 = row_start[node + 1]; }

    float S = 0.f;
    float4 acc = make_float4(0.f, 0.f, 0.f, 0.f);

    for (int i0 = j0; i0 < j1; i0 += 8) {   // same trip count across each 16-lane group
        int2 pk[8]; uint2 qk[8]; bool vk[8];
        #pragma unroll
        for (int k = 0; k < 8; ++k) {
            vk[k] = (i0 + k) < j1;
            int c = vk[k] ? (i0 + k) : i0;
            pk[k] = csr_pack[c];
        }
        #pragma unroll
        for (int k = 0; k < 8; ++k)
            qk[k] = *(const uint2*)(xl + (size_t)pk[k].x * D_H + fb);
        float t[8]; f16x2 rl[8], rh[8];
        #pragma unroll
        for (int k = 0; k < 8; ++k) {
            rl[k] = as_h2(qk[k].x);
            rh[k] = as_h2(qk[k].y);
            f16x2 a2 = as_h2((unsigned)pk[k].y);
            f16x2 m0 = a2 * we0 + (rl[k] + xr0);   // v_pk_fma + v_pk_add
            f16x2 m1 = a2 * we1 + (rh[k] + xr1);
            m0 = pk_leaky(m0, ns);                 // packed leaky relu
            m1 = pk_leaky(m1, ns);
            t[k] = fdot2a(m1, at1, fdot2a(m0, at0, 0.f));  // fp32 accum
        }
        #pragma unroll
        for (int off = 1; off <= 8; off <<= 1) {   // reduce within 16-lane group
            #pragma unroll
            for (int k = 0; k < 8; ++k) t[k] += __shfl_xor(t[k], off);
        }
        float z[8];
        #pragma unroll
        for (int k = 0; k < 8; ++k)
            z[k] = vk[k] ? __expf(t[k]) : 0.f;
        #pragma unroll
        for (int k = 0; k < 8; ++k) {
            S += z[k];
            acc.x = fmaf(z[k], (float)rl[k].x, acc.x);
            acc.y = fmaf(z[k], (float)rl[k].y, acc.y);
            acc.z = fmaf(z[k], (float)rh[k].x, acc.z);
            acc.w = fmaf(z[k], (float)rh[k].y, acc.w);
        }
    }

    if (nv) {
        float4 b4 = *(const float4*)(b + fb);
        float inv = 1.f / (S + 1e-16f);
        float4 h;
        h.x = fmaf(acc.x, inv, b4.x);
        h.y = fmaf(acc.y, inv, b4.y);
        h.z = fmaf(acc.z, inv, b4.z);
        h.w = fmaf(acc.w, inv, b4.w);
        h.x = h.x > 0.f ? h.x : expm1f(h.x);
        h.y = h.y > 0.f ? h.y : expm1f(h.y);
        h.z = h.z > 0.f ? h.z : expm1f(h.z);
        h.w = h.w > 0.f ? h.w : expm1f(h.w);
        *(float4*)(out + (size_t)node * D_H + fb) = h;
    }
}

// ---- global mean pool (batch is sorted): register accumulate, flush on change.
// r7: CHUNK 128->32 — the serial dependent-load chain (1 wave-load/iter) was
// ~16us at CHUNK=128; 4x blocks cuts the chain 4x; flush atomics stay trivial
// (~24 blocks/graph, distinct 256B regions).
__global__ void pool(const float* __restrict__ h, const int* __restrict__ batch,
                     float* __restrict__ pooled, float* __restrict__ counts) {
    const int CHUNK = 32;
    int base = blockIdx.x * CHUNK;
    int d = threadIdx.x;  // blockDim = 64
    float accv = 0.f; int cur_g = -1; int cnt = 0;
    for (int i = 0; i < CHUNK; ++i) {
        int n = base + i;
        if (n >= N_NODES) break;
        int g = batch[n];
        if (g != cur_g) {
            if (cur_g >= 0) {
                atomicAdd(&pooled[cur_g * D_H + d], accv);
                if (d == 0) atomicAdd(&counts[cur_g], (float)cnt);
            }
            cur_g = g; accv = 0.f; cnt = 0;
        }
        accv += h[(size_t)n * D_H + d];
        cnt++;
    }
    if (cur_g >= 0) {
        atomicAdd(&pooled[cur_g * D_H + d], accv);
        if (d == 0) atomicAdd(&counts[cur_g], (float)cnt);
    }
}

__global__ void classify(const float* __restrict__ pooled, const float* __restrict__ counts,
                         const float* __restrict__ Wc, const float* __restrict__ bc,
                         float* __restrict__ out) {
    int tid = threadIdx.x;             // 640 threads
    int g = tid / N_CLS, c = tid % N_CLS;
    if (g >= N_GRAPHS) return;
    float inv = 1.0f / fmaxf(counts[g], 1.0f);
    float a = bc[c];
    for (int k = 0; k < D_H; ++k)
        a = fmaf(pooled[g * D_H + k] * inv, Wc[k * N_CLS + c], a);
    out[g * N_CLS + c] = a;
}

extern "C" void kernel_launch(void* const* d_in, const int* in_sizes, int n_in,
                              void* d_out, int out_size, void* d_ws, size_t ws_size,
                              hipStream_t stream) {
    const float* x     = (const float*)d_in[0];
    const int*   ei    = (const int*)d_in[1];
    const float* eattr = (const float*)d_in[2];
    const int*   batch = (const int*)d_in[3];
    const float *Wl1 = (const float*)d_in[4],  *bl1 = (const float*)d_in[5];
    const float *Wr1 = (const float*)d_in[6],  *br1 = (const float*)d_in[7];
    const float *We1 = (const float*)d_in[8],  *att1 = (const float*)d_in[9];
    const float *b1  = (const float*)d_in[10];
    const float *Wl2 = (const float*)d_in[11], *bl2 = (const float*)d_in[12];
    const float *Wr2 = (const float*)d_in[13], *br2 = (const float*)d_in[14];
    const float *We2 = (const float*)d_in[15], *att2 = (const float*)d_in[16];
    const float *b2  = (const float*)d_in[17];
    const float *Wc  = (const float*)d_in[18], *bc = (const float*)d_in[19];
    float* out = (float*)d_out;

    const int* src = ei;
    const int* dst = ei + N_EDGES;

    // workspace layout. stg (int2, 15.36 MB) is dead after scatter; xl/xr (fp16,
    // 6.4 MB each) + h (fp32, 12.8 MB) = 25.6 MB alias its region. csr_pack kept
    // at the old 30.72 MB offset so it stays clear of xl/xr/h.
    char* base = (char*)d_ws;
    int2*  stg     = (int2*)base;                       // NB*CAP*8B = 15.36 MB
    __half* xl     = (__half*)base;                     // N*64 fp16 (6.4 MB)
    __half* xr     = xl + (size_t)N_NODES * D_H;        // N*64 fp16
    float* h       = (float*)(xr + (size_t)N_NODES * D_H); // N*64 fp32 (12.8 MB)
    int2*  csr_pack = (int2*)(base + (size_t)NB * CAP * 16); // E2 (8B) = 13.2 MB
    int*   row_start = (int*)(csr_pack + E2);           // N+1
    int*   cnt     = row_start + N_NODES + 1;           // N
    float* esum    = (float*)(cnt + N_NODES);           // 32 lines (32*PAD floats)
    int*   bcursor = (int*)(esum + 32 * PAD);           // NB lines (NB*PAD ints)
    int*   cursor  = bcursor + NB * PAD;                // N
    int*   partial = cursor + N_NODES;                  // NBLK
    float* pooled  = (float*)(partial + NBLK);          // 64*64
    float* counts  = pooled + N_GRAPHS * D_H;           // 64

    int gat_blocks = (N_NODES + 15) / 16;               // 16 nodes per 256-thr block
    int lin_blocks = (N_NODES + 31) / 32;               // 32 nodes per 256-thr block

    hipMemsetAsync(cnt, 0, (N_NODES + 32 * PAD + NB * PAD) * sizeof(int), stream);
    hipMemsetAsync(pooled, 0, (N_GRAPHS * D_H + N_GRAPHS) * sizeof(float), stream);

    // ---- CSR build: stage -> LDS hist -> scan -> slice-scatter ----
    bucket_stage<<<(N_EDGES / EPT + 255) / 256, 256, 0, stream>>>(
        src, dst, eattr, esum, bcursor, stg);
    hist_bucket<<<NB * HBB, 256, 0, stream>>>(stg, bcursor, cnt);
    scan_block<<<NBLK, SCAN_BS, 0, stream>>>(cnt, row_start, partial);
    add_offsets<<<NBLK, SCAN_BS, 0, stream>>>(row_start, partial, cursor, esum, csr_pack);
    scatter_slice<<<SLICES * 32, 1024, 0, stream>>>(stg, bcursor, row_start, csr_pack);

    // ---------------- layer 1 ----------------
    linear_dual_k<D_IN><<<lin_blocks, 256, 0, stream>>>(x, Wl1, bl1, Wr1, br1, xl, xr);
    gat_fused<<<gat_blocks, 256, 0, stream>>>(row_start, csr_pack, xl, xr, We1, att1, b1, h);

    // ---------------- layer 2 ----------------
    linear_dual_k<D_H><<<lin_blocks, 256, 0, stream>>>(h, Wl2, bl2, Wr2, br2, xl, xr);
    gat_fused<<<gat_blocks, 256, 0, stream>>>(row_start, csr_pack, xl, xr, We2, att2, b2, h);

    // ---------------- pool + classify ----------------
    pool<<<(N_NODES + 31) / 32, 64, 0, stream>>>(h, batch, pooled, counts);
    classify<<<1, 640, 0, stream>>>(pooled, counts, Wc, bc, out);
}

// Round 9
// 339.946 us; speedup vs baseline: 1.3215x; 1.3215x over previous
//
#include <hip/hip_runtime.h>
#include <hip/hip_fp16.h>
#include <math.h>

#define N_NODES 50000
#define N_EDGES 1600000
#define D_IN 128
#define D_H 64
#define N_CLS 10
#define N_GRAPHS 64
#define NEG_SLOPE 0.2f
#define E2 (N_EDGES + N_NODES)   // edges + self loops
#define SCAN_BS 256
#define NBLK ((N_NODES + SCAN_BS - 1) / SCAN_BS)   // 196 <= 256

// bucketed scatter params
#define NB 25                 // buckets: dst >> 11 (50000/2048 -> 0..24)
#define BSH 11
#define CAP 76800             // per-bucket staging capacity (>40 sigma over E/NB)
#define HBB 8                 // hist blocks per bucket
#define EPT 8                 // edges/thread in bucket_stage
#define PAD 32                // 128B stride: one cache line per contended counter
#define SLICES 8              // node-slices per bucket in scatter_slice
#define SLICE_W (2048 / SLICES)   // 256 nodes per slice

// packed fp16 via clang ext_vector — plain operators lower to v_pk_*_f16.
// (r5 lesson: ROCm 7.2 hip_fp16.h has NO __hmax2/__hmul2 half2 intrinsics.)
typedef _Float16 f16x2 __attribute__((ext_vector_type(2)));

__device__ inline f16x2 as_h2(unsigned u) { return __builtin_bit_cast(f16x2, u); }
__device__ inline int h2_as_int(f16x2 v) { return __builtin_bit_cast(int, v); }

__device__ inline f16x2 pk_leaky(f16x2 m, f16x2 ns) {
#if __has_builtin(__builtin_elementwise_max)
    return __builtin_elementwise_max(m, m * ns);
#else
    f16x2 p = m * ns, r;
    r.x = m.x > p.x ? m.x : p.x;
    r.y = m.y > p.y ? m.y : p.y;
    return r;
#endif
}

#if __has_builtin(__builtin_amdgcn_fdot2)
__device__ inline float fdot2a(f16x2 a, f16x2 b, float c) {
    return __builtin_amdgcn_fdot2(a, b, c, false);
}
#else
__device__ inline float fdot2a(f16x2 a, f16x2 b, float c) {
    return fmaf((float)a.x, (float)b.x, fmaf((float)a.y, (float)b.y, c));
}
#endif

__device__ inline float wave_reduce_sum(float v) {
    for (int off = 32; off; off >>= 1) v += __shfl_xor(v, off);
    return v;
}

// ===== pass A: bucket-stage edges + eattr sum.
// r0 fix (verified): contended-line atomics were the serializer. esum spread
// over 32 lines, bcursor one line per bucket, EPT=8, int2 staging.
// r4: eattr staged as half2(a,a) so gat's hot loop needs no per-edge cvt.
__global__ void bucket_stage(const int* __restrict__ src, const int* __restrict__ dst,
                             const float* __restrict__ eattr,
                             float* esum, int* bcursor,
                             int2* __restrict__ stg) {
    __shared__ int bcnt[4][32];
    __shared__ int woff[4][32];
    __shared__ float esh[4];
    int t = threadIdx.x;
    int wave = t >> 6;
    if (t < 128) bcnt[t >> 5][t & 31] = 0;
    __syncthreads();
    int e0 = (blockIdx.x * blockDim.x + t) * EPT;   // N_EDGES % EPT == 0
    int ss[EPT], tt[EPT], aa[EPT], r[EPT], b[EPT];
    float v = 0.f;
    bool valid = e0 < N_EDGES;
    if (valid) {
        #pragma unroll
        for (int q = 0; q < EPT / 4; ++q) {
            int4 s4 = *(const int4*)(src + e0 + 4 * q);
            int4 t4 = *(const int4*)(dst + e0 + 4 * q);
            float4 a4 = *(const float4*)(eattr + e0 + 4 * q);
            ss[4*q] = s4.x; ss[4*q+1] = s4.y; ss[4*q+2] = s4.z; ss[4*q+3] = s4.w;
            tt[4*q] = t4.x; tt[4*q+1] = t4.y; tt[4*q+2] = t4.z; tt[4*q+3] = t4.w;
            aa[4*q]   = h2_as_int((f16x2){(_Float16)a4.x, (_Float16)a4.x});
            aa[4*q+1] = h2_as_int((f16x2){(_Float16)a4.y, (_Float16)a4.y});
            aa[4*q+2] = h2_as_int((f16x2){(_Float16)a4.z, (_Float16)a4.z});
            aa[4*q+3] = h2_as_int((f16x2){(_Float16)a4.w, (_Float16)a4.w});
            v += (a4.x + a4.y) + (a4.z + a4.w);
        }
        #pragma unroll
        for (int i = 0; i < EPT; ++i) {
            b[i] = tt[i] >> BSH;
            r[i] = atomicAdd(&bcnt[wave][b[i]], 1);
        }
    }
    v = wave_reduce_sum(v);
    if ((t & 63) == 0) esh[wave] = v;
    __syncthreads();
    if (t < NB) {
        int c0 = bcnt[0][t], c1 = bcnt[1][t], c2 = bcnt[2][t], c3 = bcnt[3][t];
        int tot = c0 + c1 + c2 + c3;
        int base = tot ? atomicAdd(&bcursor[t * PAD], tot) : 0;
        woff[0][t] = base;
        woff[1][t] = base + c0;
        woff[2][t] = base + c0 + c1;
        woff[3][t] = base + c0 + c1 + c2;
    }
    if (t == 0) {
        float tot = (esh[0] + esh[1]) + (esh[2] + esh[3]);
        atomicAdd(&esum[(blockIdx.x & 31) * PAD], tot);   // 32 distinct lines
    }
    __syncthreads();
    if (valid) {
        #pragma unroll
        for (int i = 0; i < EPT; ++i) {
            int p = b[i] * CAP + woff[wave][b[i]] + r[i];
            stg[p] = make_int2((ss[i] & 0xFFFF) | ((tt[i] & 2047) << 16), aa[i]);
        }
    }
}

// ===== pass A2: per-node histogram from staged dst-low bits, LDS-resident window
__global__ void hist_bucket(const int2* __restrict__ stg, const int* __restrict__ bcursor,
                            int* cnt) {
    __shared__ int hist[2048];
    int b = blockIdx.x / HBB;
    int j = blockIdx.x % HBB;
    for (int i = threadIdx.x; i < 2048; i += 256) hist[i] = 0;
    __syncthreads();
    int n = bcursor[b * PAD];
    const int2* sd = stg + (size_t)b * CAP;
    int per = (n + HBB - 1) / HBB;
    int start = j * per;
    int end = min(start + per, n);
    for (int idx = start + threadIdx.x; idx < end; idx += 256)
        atomicAdd(&hist[(sd[idx].x >> 16) & 2047], 1);
    __syncthreads();
    int nb = b << BSH;
    for (int i = threadIdx.x; i < 2048; i += 256) {
        int c = hist[i];
        if (c) atomicAdd(&cnt[nb + i], c);
    }
}

// ---- block-local exclusive scan; +1 per node folds in the self-loop slot ----
__global__ void scan_block(const int* __restrict__ cnt, int* __restrict__ row_start,
                           int* __restrict__ partial) {
    __shared__ int sd[SCAN_BS];
    int i = blockIdx.x * SCAN_BS + threadIdx.x;
    int v = (i < N_NODES) ? (cnt[i] + 1) : 0;   // +1 = self loop
    sd[threadIdx.x] = v;
    __syncthreads();
    for (int off = 1; off < SCAN_BS; off <<= 1) {
        int t = (threadIdx.x >= off) ? sd[threadIdx.x - off] : 0;
        __syncthreads();
        sd[threadIdx.x] += t;
        __syncthreads();
    }
    if (i < N_NODES) row_start[i] = sd[threadIdx.x] - v;
    if (threadIdx.x == SCAN_BS - 1) partial[blockIdx.x] = sd[threadIdx.x];
}
// finalize row_start (redundant LDS scan of partials replaces a launch),
// write self-loop CSR entry (eattr-mean as half2), seed cursor
__global__ void add_offsets(int* __restrict__ row_start, const int* __restrict__ partial,
                            int* __restrict__ cursor, const float* __restrict__ esum,
                            int2* __restrict__ csr_pack) {
    __shared__ int sp[SCAN_BS];
    int pv = (threadIdx.x < NBLK) ? partial[threadIdx.x] : 0;
    sp[threadIdx.x] = pv;
    __syncthreads();
    for (int off = 1; off < SCAN_BS; off <<= 1) {
        int t = (threadIdx.x >= off) ? sp[threadIdx.x - off] : 0;
        __syncthreads();
        sp[threadIdx.x] += t;
        __syncthreads();
    }
    float es = 0.f;
    #pragma unroll
    for (int jj = 0; jj < 32; ++jj) es += esum[jj * PAD];
    float esm = es * (1.0f / N_EDGES);
    int ebits = h2_as_int((f16x2){(_Float16)esm, (_Float16)esm});
    int base = (blockIdx.x == 0) ? 0 : sp[blockIdx.x - 1];
    int i = blockIdx.x * SCAN_BS + threadIdx.x;
    if (i < N_NODES) {
        int r = row_start[i] + base;
        row_start[i] = r;
        csr_pack[r] = make_int2(i, ebits);
        cursor[i] = r + 1;
    }
    if (i == 0) row_start[N_NODES] = E2;
}

// ===== pass B (r3-verified): slice-owned scatter, LDS cursors, deep MLP.
__global__ __launch_bounds__(1024) void scatter_slice(
                              const int2* __restrict__ stg,
                              const int* __restrict__ bcursor,
                              const int* __restrict__ row_start,
                              int2* __restrict__ csr_pack) {
    __shared__ int lcur[SLICE_W];
    int b = blockIdx.x & 31;
    int m = blockIdx.x >> 5;
    if (b >= NB) return;
    int nbase = (b << BSH) + m * SLICE_W;
    for (int i = threadIdx.x; i < SLICE_W; i += 1024) {
        int node = nbase + i;
        lcur[i] = (node < N_NODES) ? row_start[node] + 1 : 0;  // +1 skips self-loop slot
    }
    __syncthreads();
    int n = bcursor[b * PAD];
    const int4* sd4 = (const int4*)(stg + (size_t)b * CAP);   // b*CAP*8B is 16B-aligned
    int n4 = n >> 1;
    int lo = m * SLICE_W, hi = lo + SLICE_W;
    for (int base4 = 0; base4 < n4; base4 += 4096) {
        int4 e[4];
        int idx[4];
        #pragma unroll
        for (int j = 0; j < 4; ++j) {
            idx[j] = base4 + j * 1024 + (int)threadIdx.x;
            if (idx[j] < n4) e[j] = sd4[idx[j]];
        }
        #pragma unroll
        for (int j = 0; j < 4; ++j) {
            if (idx[j] < n4) {
                int dl0 = (e[j].x >> 16) & 2047;
                if (dl0 >= lo && dl0 < hi) {
                    int q = atomicAdd(&lcur[dl0 - lo], 1);
                    csr_pack[q] = make_int2(e[j].x & 0xFFFF, e[j].y);
                }
                int dl1 = (e[j].z >> 16) & 2047;
                if (dl1 >= lo && dl1 < hi) {
                    int q = atomicAdd(&lcur[dl1 - lo], 1);
                    csr_pack[q] = make_int2(e[j].z & 0xFFFF, e[j].w);
                }
            }
        }
    }
    if ((n & 1) && threadIdx.x == 0) {   // odd tail edge; only owning slice stores
        int2 e = stg[(size_t)b * CAP + n - 1];
        int dl = (e.x >> 16) & 2047;
        if (dl >= lo && dl < hi) {
            int q = atomicAdd(&lcur[dl - lo], 1);
            csr_pack[q] = make_int2(e.x & 0xFFFF, e.y);
        }
    }
}

// ---- xl = x@Wl + bl ; xr = x@Wr + br -> fp16 outputs.
// r8: REVERT to the r1/r6-verified LDS-broadcast structure (r7's no-LDS
// weight-streaming version hit L2 latency every iter with a serialized
// load chain: 120us, VALUBusy 10%. Lesson: per-iter-reused weights need
// LDS/registers). One change vs r6: TN 64->32. r6 was GRID-limited (782
// blocks = 3/CU = 12 waves/CU, occupancy 24%); TN=32 -> 1563 blocks ->
// ~6 blocks/CU, double the resident waves. LDS 16KB (K=128) / 8KB (K=64).
template<int K>
__global__ __launch_bounds__(256) void linear_dual_k(
                              const float* __restrict__ x,
                              const float* __restrict__ Wl, const float* __restrict__ bl,
                              const float* __restrict__ Wr, const float* __restrict__ br,
                              __half* __restrict__ xl, __half* __restrict__ xr) {
    const int TN = 32;            // nodes per block
    const int NPW = TN / 4;       // 8 nodes per wave
    __shared__ float xs[TN * K];  // 16KB (K=128) / 8KB (K=64)
    int t = threadIdx.x;
    int nb = blockIdx.x * TN;
    int rem = N_NODES - nb;
    int tot4 = (rem >= TN ? TN : rem) * (K / 4);
    const float4* xg = (const float4*)(x + (size_t)nb * K);
    float4* xs4 = (float4*)xs;
    for (int i = t; i < tot4; i += 256) xs4[i] = xg[i];
    __syncthreads();
    int wave = t >> 6, d = t & 63;
    int n0 = wave * NPW;
    float blv = bl[d], brv = br[d];
    float al[NPW], ar[NPW];
    #pragma unroll
    for (int i = 0; i < NPW; ++i) { al[i] = blv; ar[i] = brv; }
    #pragma unroll 2
    for (int k4 = 0; k4 < K / 4; ++k4) {
        int kb = k4 * 4;
        float wl[4], wr[4];
        #pragma unroll
        for (int q = 0; q < 4; ++q) {
            wl[q] = Wl[(kb + q) * D_H + d];
            wr[q] = Wr[(kb + q) * D_H + d];
        }
        #pragma unroll
        for (int i = 0; i < NPW; ++i) {
            float4 xv = *(const float4*)&xs[(n0 + i) * K + kb];  // LDS broadcast
            al[i] = fmaf(xv.x, wl[0], al[i]);
            al[i] = fmaf(xv.y, wl[1], al[i]);
            al[i] = fmaf(xv.z, wl[2], al[i]);
            al[i] = fmaf(xv.w, wl[3], al[i]);
            ar[i] = fmaf(xv.x, wr[0], ar[i]);
            ar[i] = fmaf(xv.y, wr[1], ar[i]);
            ar[i] = fmaf(xv.z, wr[2], ar[i]);
            ar[i] = fmaf(xv.w, wr[3], ar[i]);
        }
    }
    #pragma unroll
    for (int i = 0; i < NPW; ++i) {
        int g = nb + n0 + i;
        if (g < N_NODES) {
            xl[(size_t)g * D_H + d] = __float2half(al[i]);
            xr[(size_t)g * D_H + d] = __float2half(ar[i]);
        }
    }
}

// ---- fused GATv2 layer — r6-verified design; r7: 8 edges/iter for gather MLP
// (kept: r8 totals imply gat+pool saved ~60us in the r7 run).
__global__ __launch_bounds__(256) void gat_fused(
        const int* __restrict__ row_start, const int2* __restrict__ csr_pack,
        const __half* __restrict__ xl, const __half* __restrict__ xr,
        const float* __restrict__ We, const float* __restrict__ att,
        const float* __restrict__ b, float* __restrict__ out) {
    int lane = threadIdx.x & 63;
    int g = lane >> 4;
    int s = lane & 15;
    int wid = blockIdx.x * (blockDim.x >> 6) + (threadIdx.x >> 6);
    int node = wid * 4 + g;                 // 16 nodes per 256-thread block
    bool nv = node < N_NODES;
    int nodec = nv ? node : 0;
    int fb = s * 4;
    float4 we4  = *(const float4*)(We + fb);
    float4 att4 = *(const float4*)(att + fb);
    f16x2 we0 = {(_Float16)we4.x, (_Float16)we4.y};
    f16x2 we1 = {(_Float16)we4.z, (_Float16)we4.w};
    f16x2 at0 = {(_Float16)att4.x, (_Float16)att4.y};
    f16x2 at1 = {(_Float16)att4.z, (_Float16)att4.w};
    uint2 xru = *(const uint2*)(xr + (size_t)nodec * D_H + fb);
    f16x2 xr0 = as_h2(xru.x), xr1 = as_h2(xru.y);
    const f16x2 ns = {(_Float16)NEG_SLOPE, (_Float16)NEG_SLOPE};
    int j0 = 0, j1 = 0;
    if (nv) { j0 = row_start[node]; j1 = row_start[node + 1]; }

    float S = 0.f;
    float4 acc = make_float4(0.f, 0.f, 0.f, 0.f);

    for (int i0 = j0; i0 < j1; i0 += 8) {   // same trip count across each 16-lane group
        int2 pk[8]; uint2 qk[8]; bool vk[8];
        #pragma unroll
        for (int k = 0; k < 8; ++k) {
            vk[k] = (i0 + k) < j1;
            int c = vk[k] ? (i0 + k) : i0;
            pk[k] = csr_pack[c];
        }
        #pragma unroll
        for (int k = 0; k < 8; ++k)
            qk[k] = *(const uint2*)(xl + (size_t)pk[k].x * D_H + fb);
        float t[8]; f16x2 rl[8], rh[8];
        #pragma unroll
        for (int k = 0; k < 8; ++k) {
            rl[k] = as_h2(qk[k].x);
            rh[k] = as_h2(qk[k].y);
            f16x2 a2 = as_h2((unsigned)pk[k].y);
            f16x2 m0 = a2 * we0 + (rl[k] + xr0);   // v_pk_fma + v_pk_add
            f16x2 m1 = a2 * we1 + (rh[k] + xr1);
            m0 = pk_leaky(m0, ns);                 // packed leaky relu
            m1 = pk_leaky(m1, ns);
            t[k] = fdot2a(m1, at1, fdot2a(m0, at0, 0.f));  // fp32 accum
        }
        #pragma unroll
        for (int off = 1; off <= 8; off <<= 1) {   // reduce within 16-lane group
            #pragma unroll
            for (int k = 0; k < 8; ++k) t[k] += __shfl_xor(t[k], off);
        }
        float z[8];
        #pragma unroll
        for (int k = 0; k < 8; ++k)
            z[k] = vk[k] ? __expf(t[k]) : 0.f;
        #pragma unroll
        for (int k = 0; k < 8; ++k) {
            S += z[k];
            acc.x = fmaf(z[k], (float)rl[k].x, acc.x);
            acc.y = fmaf(z[k], (float)rl[k].y, acc.y);
            acc.z = fmaf(z[k], (float)rh[k].x, acc.z);
            acc.w = fmaf(z[k], (float)rh[k].y, acc.w);
        }
    }

    if (nv) {
        float4 b4 = *(const float4*)(b + fb);
        float inv = 1.f / (S + 1e-16f);
        float4 h;
        h.x = fmaf(acc.x, inv, b4.x);
        h.y = fmaf(acc.y, inv, b4.y);
        h.z = fmaf(acc.z, inv, b4.z);
        h.w = fmaf(acc.w, inv, b4.w);
        h.x = h.x > 0.f ? h.x : expm1f(h.x);
        h.y = h.y > 0.f ? h.y : expm1f(h.y);
        h.z = h.z > 0.f ? h.z : expm1f(h.z);
        h.w = h.w > 0.f ? h.w : expm1f(h.w);
        *(float4*)(out + (size_t)node * D_H + fb) = h;
    }
}

// ---- global mean pool (batch is sorted): register accumulate, flush on change.
// r7 (kept): CHUNK=32 — 4x shorter serial dependent-load chain than 128.
__global__ void pool(const float* __restrict__ h, const int* __restrict__ batch,
                     float* __restrict__ pooled, float* __restrict__ counts) {
    const int CHUNK = 32;
    int base = blockIdx.x * CHUNK;
    int d = threadIdx.x;  // blockDim = 64
    float accv = 0.f; int cur_g = -1; int cnt = 0;
    for (int i = 0; i < CHUNK; ++i) {
        int n = base + i;
        if (n >= N_NODES) break;
        int g = batch[n];
        if (g != cur_g) {
            if (cur_g >= 0) {
                atomicAdd(&pooled[cur_g * D_H + d], accv);
                if (d == 0) atomicAdd(&counts[cur_g], (float)cnt);
            }
            cur_g = g; accv = 0.f; cnt = 0;
        }
        accv += h[(size_t)n * D_H + d];
        cnt++;
    }
    if (cur_g >= 0) {
        atomicAdd(&pooled[cur_g * D_H + d], accv);
        if (d == 0) atomicAdd(&counts[cur_g], (float)cnt);
    }
}

__global__ void classify(const float* __restrict__ pooled, const float* __restrict__ counts,
                         const float* __restrict__ Wc, const float* __restrict__ bc,
                         float* __restrict__ out) {
    int tid = threadIdx.x;             // 640 threads
    int g = tid / N_CLS, c = tid % N_CLS;
    if (g >= N_GRAPHS) return;
    float inv = 1.0f / fmaxf(counts[g], 1.0f);
    float a = bc[c];
    for (int k = 0; k < D_H; ++k)
        a = fmaf(pooled[g * D_H + k] * inv, Wc[k * N_CLS + c], a);
    out[g * N_CLS + c] = a;
}

extern "C" void kernel_launch(void* const* d_in, const int* in_sizes, int n_in,
                              void* d_out, int out_size, void* d_ws, size_t ws_size,
                              hipStream_t stream) {
    const float* x     = (const float*)d_in[0];
    const int*   ei    = (const int*)d_in[1];
    const float* eattr = (const float*)d_in[2];
    const int*   batch = (const int*)d_in[3];
    const float *Wl1 = (const float*)d_in[4],  *bl1 = (const float*)d_in[5];
    const float *Wr1 = (const float*)d_in[6],  *br1 = (const float*)d_in[7];
    const float *We1 = (const float*)d_in[8],  *att1 = (const float*)d_in[9];
    const float *b1  = (const float*)d_in[10];
    const float *Wl2 = (const float*)d_in[11], *bl2 = (const float*)d_in[12];
    const float *Wr2 = (const float*)d_in[13], *br2 = (const float*)d_in[14];
    const float *We2 = (const float*)d_in[15], *att2 = (const float*)d_in[16];
    const float *b2  = (const float*)d_in[17];
    const float *Wc  = (const float*)d_in[18], *bc = (const float*)d_in[19];
    float* out = (float*)d_out;

    const int* src = ei;
    const int* dst = ei + N_EDGES;

    // workspace layout. stg (int2, 15.36 MB) is dead after scatter; xl/xr (fp16,
    // 6.4 MB each) + h (fp32, 12.8 MB) = 25.6 MB alias its region. csr_pack kept
    // at the old 30.72 MB offset so it stays clear of xl/xr/h.
    char* base = (char*)d_ws;
    int2*  stg     = (int2*)base;                       // NB*CAP*8B = 15.36 MB
    __half* xl     = (__half*)base;                     // N*64 fp16 (6.4 MB)
    __half* xr     = xl + (size_t)N_NODES * D_H;        // N*64 fp16
    float* h       = (float*)(xr + (size_t)N_NODES * D_H); // N*64 fp32 (12.8 MB)
    int2*  csr_pack = (int2*)(base + (size_t)NB * CAP * 16); // E2 (8B) = 13.2 MB
    int*   row_start = (int*)(csr_pack + E2);           // N+1
    int*   cnt     = row_start + N_NODES + 1;           // N
    float* esum    = (float*)(cnt + N_NODES);           // 32 lines (32*PAD floats)
    int*   bcursor = (int*)(esum + 32 * PAD);           // NB lines (NB*PAD ints)
    int*   cursor  = bcursor + NB * PAD;                // N
    int*   partial = cursor + N_NODES;                  // NBLK
    float* pooled  = (float*)(partial + NBLK);          // 64*64
    float* counts  = pooled + N_GRAPHS * D_H;           // 64

    int gat_blocks = (N_NODES + 15) / 16;               // 16 nodes per 256-thr block
    int lin_blocks = (N_NODES + 31) / 32;               // 32 nodes per block (TN=32)

    hipMemsetAsync(cnt, 0, (N_NODES + 32 * PAD + NB * PAD) * sizeof(int), stream);
    hipMemsetAsync(pooled, 0, (N_GRAPHS * D_H + N_GRAPHS) * sizeof(float), stream);

    // ---- CSR build: stage -> LDS hist -> scan -> slice-scatter ----
    bucket_stage<<<(N_EDGES / EPT + 255) / 256, 256, 0, stream>>>(
        src, dst, eattr, esum, bcursor, stg);
    hist_bucket<<<NB * HBB, 256, 0, stream>>>(stg, bcursor, cnt);
    scan_block<<<NBLK, SCAN_BS, 0, stream>>>(cnt, row_start, partial);
    add_offsets<<<NBLK, SCAN_BS, 0, stream>>>(row_start, partial, cursor, esum, csr_pack);
    scatter_slice<<<SLICES * 32, 1024, 0, stream>>>(stg, bcursor, row_start, csr_pack);

    // ---------------- layer 1 ----------------
    linear_dual_k<D_IN><<<lin_blocks, 256, 0, stream>>>(x, Wl1, bl1, Wr1, br1, xl, xr);
    gat_fused<<<gat_blocks, 256, 0, stream>>>(row_start, csr_pack, xl, xr, We1, att1, b1, h);

    // ---------------- layer 2 ----------------
    linear_dual_k<D_H><<<lin_blocks, 256, 0, stream>>>(h, Wl2, bl2, Wr2, br2, xl, xr);
    gat_fused<<<gat_blocks, 256, 0, stream>>>(row_start, csr_pack, xl, xr, We2, att2, b2, h);

    // ---------------- pool + classify ----------------
    pool<<<(N_NODES + 31) / 32, 64, 0, stream>>>(h, batch, pooled, counts);
    classify<<<1, 640, 0, stream>>>(pooled, counts, Wc, bc, out);
}

// Round 10
// 334.188 us; speedup vs baseline: 1.3443x; 1.0172x over previous
//
#include <hip/hip_runtime.h>
#include <hip/hip_fp16.h>
#include <math.h>

#define N_NODES 50000
#define N_EDGES 1600000
#define D_IN 128
#define D_H 64
#define N_CLS 10
#define N_GRAPHS 64
#define NEG_SLOPE 0.2f
#define E2 (N_EDGES + N_NODES)   // edges + self loops
#define SCAN_BS 256
#define NBLK ((N_NODES + SCAN_BS - 1) / SCAN_BS)   // 196 <= 256

// bucketed scatter params
#define NB 25                 // buckets: dst >> 11 (50000/2048 -> 0..24)
#define BSH 11
#define CAP 76800             // per-bucket staging capacity (>40 sigma over E/NB)
#define HBB 8                 // hist blocks per bucket
#define EPT 8                 // edges/thread in bucket_stage
#define PAD 32                // 128B stride: one cache line per contended counter
#define SLICES 8              // node-slices per bucket in scatter_slice
#define SLICE_W (2048 / SLICES)   // 256 nodes per slice

// packed fp16 via clang ext_vector — plain operators lower to v_pk_*_f16.
// (r5 lesson: ROCm 7.2 hip_fp16.h has NO __hmax2/__hmul2 half2 intrinsics.)
typedef _Float16 f16x2 __attribute__((ext_vector_type(2)));

__device__ inline f16x2 as_h2(unsigned u) { return __builtin_bit_cast(f16x2, u); }
__device__ inline int h2_as_int(f16x2 v) { return __builtin_bit_cast(int, v); }

__device__ inline f16x2 pk_leaky(f16x2 m, f16x2 ns) {
#if __has_builtin(__builtin_elementwise_max)
    return __builtin_elementwise_max(m, m * ns);
#else
    f16x2 p = m * ns, r;
    r.x = m.x > p.x ? m.x : p.x;
    r.y = m.y > p.y ? m.y : p.y;
    return r;
#endif
}

#if __has_builtin(__builtin_amdgcn_fdot2)
__device__ inline float fdot2a(f16x2 a, f16x2 b, float c) {
    return __builtin_amdgcn_fdot2(a, b, c, false);
}
#else
__device__ inline float fdot2a(f16x2 a, f16x2 b, float c) {
    return fmaf((float)a.x, (float)b.x, fmaf((float)a.y, (float)b.y, c));
}
#endif

__device__ inline float wave_reduce_sum(float v) {
    for (int off = 32; off; off >>= 1) v += __shfl_xor(v, off);
    return v;
}

// ===== pass A: bucket-stage edges + eattr sum.
// r0 fix (verified): contended-line atomics were the serializer. esum spread
// over 32 lines, bcursor one line per bucket, EPT=8, int2 staging.
// r4: eattr staged as half2(a,a) so gat's hot loop needs no per-edge cvt.
__global__ void bucket_stage(const int* __restrict__ src, const int* __restrict__ dst,
                             const float* __restrict__ eattr,
                             float* esum, int* bcursor,
                             int2* __restrict__ stg) {
    __shared__ int bcnt[4][32];
    __shared__ int woff[4][32];
    __shared__ float esh[4];
    int t = threadIdx.x;
    int wave = t >> 6;
    if (t < 128) bcnt[t >> 5][t & 31] = 0;
    __syncthreads();
    int e0 = (blockIdx.x * blockDim.x + t) * EPT;   // N_EDGES % EPT == 0
    int ss[EPT], tt[EPT], aa[EPT], r[EPT], b[EPT];
    float v = 0.f;
    bool valid = e0 < N_EDGES;
    if (valid) {
        #pragma unroll
        for (int q = 0; q < EPT / 4; ++q) {
            int4 s4 = *(const int4*)(src + e0 + 4 * q);
            int4 t4 = *(const int4*)(dst + e0 + 4 * q);
            float4 a4 = *(const float4*)(eattr + e0 + 4 * q);
            ss[4*q] = s4.x; ss[4*q+1] = s4.y; ss[4*q+2] = s4.z; ss[4*q+3] = s4.w;
            tt[4*q] = t4.x; tt[4*q+1] = t4.y; tt[4*q+2] = t4.z; tt[4*q+3] = t4.w;
            aa[4*q]   = h2_as_int((f16x2){(_Float16)a4.x, (_Float16)a4.x});
            aa[4*q+1] = h2_as_int((f16x2){(_Float16)a4.y, (_Float16)a4.y});
            aa[4*q+2] = h2_as_int((f16x2){(_Float16)a4.z, (_Float16)a4.z});
            aa[4*q+3] = h2_as_int((f16x2){(_Float16)a4.w, (_Float16)a4.w});
            v += (a4.x + a4.y) + (a4.z + a4.w);
        }
        #pragma unroll
        for (int i = 0; i < EPT; ++i) {
            b[i] = tt[i] >> BSH;
            r[i] = atomicAdd(&bcnt[wave][b[i]], 1);
        }
    }
    v = wave_reduce_sum(v);
    if ((t & 63) == 0) esh[wave] = v;
    __syncthreads();
    if (t < NB) {
        int c0 = bcnt[0][t], c1 = bcnt[1][t], c2 = bcnt[2][t], c3 = bcnt[3][t];
        int tot = c0 + c1 + c2 + c3;
        int base = tot ? atomicAdd(&bcursor[t * PAD], tot) : 0;
        woff[0][t] = base;
        woff[1][t] = base + c0;
        woff[2][t] = base + c0 + c1;
        woff[3][t] = base + c0 + c1 + c2;
    }
    if (t == 0) {
        float tot = (esh[0] + esh[1]) + (esh[2] + esh[3]);
        atomicAdd(&esum[(blockIdx.x & 31) * PAD], tot);   // 32 distinct lines
    }
    __syncthreads();
    if (valid) {
        #pragma unroll
        for (int i = 0; i < EPT; ++i) {
            int p = b[i] * CAP + woff[wave][b[i]] + r[i];
            stg[p] = make_int2((ss[i] & 0xFFFF) | ((tt[i] & 2047) << 16), aa[i]);
        }
    }
}

// ===== pass A2: per-node histogram from staged dst-low bits, LDS-resident window
__global__ void hist_bucket(const int2* __restrict__ stg, const int* __restrict__ bcursor,
                            int* cnt) {
    __shared__ int hist[2048];
    int b = blockIdx.x / HBB;
    int j = blockIdx.x % HBB;
    for (int i = threadIdx.x; i < 2048; i += 256) hist[i] = 0;
    __syncthreads();
    int n = bcursor[b * PAD];
    const int2* sd = stg + (size_t)b * CAP;
    int per = (n + HBB - 1) / HBB;
    int start = j * per;
    int end = min(start + per, n);
    for (int idx = start + threadIdx.x; idx < end; idx += 256)
        atomicAdd(&hist[(sd[idx].x >> 16) & 2047], 1);
    __syncthreads();
    int nb = b << BSH;
    for (int i = threadIdx.x; i < 2048; i += 256) {
        int c = hist[i];
        if (c) atomicAdd(&cnt[nb + i], c);
    }
}

// ---- block-local exclusive scan; +1 per node folds in the self-loop slot ----
__global__ void scan_block(const int* __restrict__ cnt, int* __restrict__ row_start,
                           int* __restrict__ partial) {
    __shared__ int sd[SCAN_BS];
    int i = blockIdx.x * SCAN_BS + threadIdx.x;
    int v = (i < N_NODES) ? (cnt[i] + 1) : 0;   // +1 = self loop
    sd[threadIdx.x] = v;
    __syncthreads();
    for (int off = 1; off < SCAN_BS; off <<= 1) {
        int t = (threadIdx.x >= off) ? sd[threadIdx.x - off] : 0;
        __syncthreads();
        sd[threadIdx.x] += t;
        __syncthreads();
    }
    if (i < N_NODES) row_start[i] = sd[threadIdx.x] - v;
    if (threadIdx.x == SCAN_BS - 1) partial[blockIdx.x] = sd[threadIdx.x];
}
// finalize row_start (redundant LDS scan of partials replaces a launch),
// write self-loop CSR entry (eattr-mean as half2), seed cursor
__global__ void add_offsets(int* __restrict__ row_start, const int* __restrict__ partial,
                            int* __restrict__ cursor, const float* __restrict__ esum,
                            int2* __restrict__ csr_pack) {
    __shared__ int sp[SCAN_BS];
    int pv = (threadIdx.x < NBLK) ? partial[threadIdx.x] : 0;
    sp[threadIdx.x] = pv;
    __syncthreads();
    for (int off = 1; off < SCAN_BS; off <<= 1) {
        int t = (threadIdx.x >= off) ? sp[threadIdx.x - off] : 0;
        __syncthreads();
        sp[threadIdx.x] += t;
        __syncthreads();
    }
    float es = 0.f;
    #pragma unroll
    for (int jj = 0; jj < 32; ++jj) es += esum[jj * PAD];
    float esm = es * (1.0f / N_EDGES);
    int ebits = h2_as_int((f16x2){(_Float16)esm, (_Float16)esm});
    int base = (blockIdx.x == 0) ? 0 : sp[blockIdx.x - 1];
    int i = blockIdx.x * SCAN_BS + threadIdx.x;
    if (i < N_NODES) {
        int r = row_start[i] + base;
        row_start[i] = r;
        csr_pack[r] = make_int2(i, ebits);
        cursor[i] = r + 1;
    }
    if (i == 0) row_start[N_NODES] = E2;
}

// ===== pass B (r3-verified): slice-owned scatter, LDS cursors, deep MLP.
__global__ __launch_bounds__(1024) void scatter_slice(
                              const int2* __restrict__ stg,
                              const int* __restrict__ bcursor,
                              const int* __restrict__ row_start,
                              int2* __restrict__ csr_pack) {
    __shared__ int lcur[SLICE_W];
    int b = blockIdx.x & 31;
    int m = blockIdx.x >> 5;
    if (b >= NB) return;
    int nbase = (b << BSH) + m * SLICE_W;
    for (int i = threadIdx.x; i < SLICE_W; i += 1024) {
        int node = nbase + i;
        lcur[i] = (node < N_NODES) ? row_start[node] + 1 : 0;  // +1 skips self-loop slot
    }
    __syncthreads();
    int n = bcursor[b * PAD];
    const int4* sd4 = (const int4*)(stg + (size_t)b * CAP);   // b*CAP*8B is 16B-aligned
    int n4 = n >> 1;
    int lo = m * SLICE_W, hi = lo + SLICE_W;
    for (int base4 = 0; base4 < n4; base4 += 4096) {
        int4 e[4];
        int idx[4];
        #pragma unroll
        for (int j = 0; j < 4; ++j) {
            idx[j] = base4 + j * 1024 + (int)threadIdx.x;
            if (idx[j] < n4) e[j] = sd4[idx[j]];
        }
        #pragma unroll
        for (int j = 0; j < 4; ++j) {
            if (idx[j] < n4) {
                int dl0 = (e[j].x >> 16) & 2047;
                if (dl0 >= lo && dl0 < hi) {
                    int q = atomicAdd(&lcur[dl0 - lo], 1);
                    csr_pack[q] = make_int2(e[j].x & 0xFFFF, e[j].y);
                }
                int dl1 = (e[j].z >> 16) & 2047;
                if (dl1 >= lo && dl1 < hi) {
                    int q = atomicAdd(&lcur[dl1 - lo], 1);
                    csr_pack[q] = make_int2(e[j].z & 0xFFFF, e[j].w);
                }
            }
        }
    }
    if ((n & 1) && threadIdx.x == 0) {   // odd tail edge; only owning slice stores
        int2 e = stg[(size_t)b * CAP + n - 1];
        int dl = (e.x >> 16) & 2047;
        if (dl >= lo && dl < hi) {
            int q = atomicAdd(&lcur[dl - lo], 1);
            csr_pack[q] = make_int2(e.x & 0xFFFF, e.y);
        }
    }
}

// ---- xl = x@Wl + bl ; xr = x@Wr + br -> fp16 outputs.
// r8-verified: LDS-broadcast structure, TN=32 for grid-limited occupancy.
// (r7 lesson: per-iter-reused weights must come from LDS/regs, not L2.)
template<int K>
__global__ __launch_bounds__(256) void linear_dual_k(
                              const float* __restrict__ x,
                              const float* __restrict__ Wl, const float* __restrict__ bl,
                              const float* __restrict__ Wr, const float* __restrict__ br,
                              __half* __restrict__ xl, __half* __restrict__ xr) {
    const int TN = 32;            // nodes per block
    const int NPW = TN / 4;       // 8 nodes per wave
    __shared__ float xs[TN * K];  // 16KB (K=128) / 8KB (K=64)
    int t = threadIdx.x;
    int nb = blockIdx.x * TN;
    int rem = N_NODES - nb;
    int tot4 = (rem >= TN ? TN : rem) * (K / 4);
    const float4* xg = (const float4*)(x + (size_t)nb * K);
    float4* xs4 = (float4*)xs;
    for (int i = t; i < tot4; i += 256) xs4[i] = xg[i];
    __syncthreads();
    int wave = t >> 6, d = t & 63;
    int n0 = wave * NPW;
    float blv = bl[d], brv = br[d];
    float al[NPW], ar[NPW];
    #pragma unroll
    for (int i = 0; i < NPW; ++i) { al[i] = blv; ar[i] = brv; }
    #pragma unroll 2
    for (int k4 = 0; k4 < K / 4; ++k4) {
        int kb = k4 * 4;
        float wl[4], wr[4];
        #pragma unroll
        for (int q = 0; q < 4; ++q) {
            wl[q] = Wl[(kb + q) * D_H + d];
            wr[q] = Wr[(kb + q) * D_H + d];
        }
        #pragma unroll
        for (int i = 0; i < NPW; ++i) {
            float4 xv = *(const float4*)&xs[(n0 + i) * K + kb];  // LDS broadcast
            al[i] = fmaf(xv.x, wl[0], al[i]);
            al[i] = fmaf(xv.y, wl[1], al[i]);
            al[i] = fmaf(xv.z, wl[2], al[i]);
            al[i] = fmaf(xv.w, wl[3], al[i]);
            ar[i] = fmaf(xv.x, wr[0], ar[i]);
            ar[i] = fmaf(xv.y, wr[1], ar[i]);
            ar[i] = fmaf(xv.z, wr[2], ar[i]);
            ar[i] = fmaf(xv.w, wr[3], ar[i]);
        }
    }
    #pragma unroll
    for (int i = 0; i < NPW; ++i) {
        int g = nb + n0 + i;
        if (g < N_NODES) {
            xl[(size_t)g * D_H + d] = __float2half(al[i]);
            xr[(size_t)g * D_H + d] = __float2half(ar[i]);
        }
    }
}

// ---- fused GATv2 layer — r9: 8-LANE groups (8 dims/lane, 8 nodes/wave),
// 4 edges/iter. vs r8's 16-lane groups: gather loads per edge-slot halve
// (int4 16B/lane covers a 128B row with 8 lanes), reduce is 3 shuffle steps
// not 4, ~26% fewer wave-instructions per edge-slot, 8 gathers in flight per
// wave. r8 counters motivating this: VALUBusy 63% + 37% gather stall; 8/iter
// at VGPR=40 had serialized into sub-batches (48.9us ~= r6's 48.2).
__global__ __launch_bounds__(256) void gat_fused(
        const int* __restrict__ row_start, const int2* __restrict__ csr_pack,
        const __half* __restrict__ xl, const __half* __restrict__ xr,
        const float* __restrict__ We, const float* __restrict__ att,
        const float* __restrict__ b, float* __restrict__ out) {
    int lane = threadIdx.x & 63;
    int g = lane >> 3;                      // 8 groups per wave
    int s = lane & 7;                       // 8 lanes per group
    int wid = blockIdx.x * (blockDim.x >> 6) + (threadIdx.x >> 6);
    int node = wid * 8 + g;                 // 32 nodes per 256-thread block
    bool nv = node < N_NODES;
    int nodec = nv ? node : 0;
    int fb = s * 8;                         // 8 dims per lane
    float4 wea = *(const float4*)(We + fb), web = *(const float4*)(We + fb + 4);
    float4 ata = *(const float4*)(att + fb), atb = *(const float4*)(att + fb + 4);
    f16x2 we[4] = {{(_Float16)wea.x, (_Float16)wea.y}, {(_Float16)wea.z, (_Float16)wea.w},
                   {(_Float16)web.x, (_Float16)web.y}, {(_Float16)web.z, (_Float16)web.w}};
    f16x2 at[4] = {{(_Float16)ata.x, (_Float16)ata.y}, {(_Float16)ata.z, (_Float16)ata.w},
                   {(_Float16)atb.x, (_Float16)atb.y}, {(_Float16)atb.z, (_Float16)atb.w}};
    int4 xru = *(const int4*)(xr + (size_t)nodec * D_H + fb);   // 16B, aligned
    f16x2 xr4[4] = {as_h2((unsigned)xru.x), as_h2((unsigned)xru.y),
                    as_h2((unsigned)xru.z), as_h2((unsigned)xru.w)};
    const f16x2 ns = {(_Float16)NEG_SLOPE, (_Float16)NEG_SLOPE};
    int j0 = 0, j1 = 0;
    if (nv) { j0 = row_start[node]; j1 = row_start[node + 1]; }

    float S = 0.f;
    float acc[8] = {0.f, 0.f, 0.f, 0.f, 0.f, 0.f, 0.f, 0.f};

    for (int i0 = j0; i0 < j1; i0 += 4) {   // same trip count across each 8-lane group
        int2 pk[4]; int4 qk[4]; bool vk[4];
        #pragma unroll
        for (int k = 0; k < 4; ++k) {
            vk[k] = (i0 + k) < j1;
            int c = vk[k] ? (i0 + k) : i0;
            pk[k] = csr_pack[c];
        }
        #pragma unroll
        for (int k = 0; k < 4; ++k)
            qk[k] = *(const int4*)(xl + (size_t)pk[k].x * D_H + fb);   // 16B gather
        float t[4];
        #pragma unroll
        for (int k = 0; k < 4; ++k) {
            f16x2 a2 = as_h2((unsigned)pk[k].y);
            f16x2 r0 = as_h2((unsigned)qk[k].x), r1 = as_h2((unsigned)qk[k].y);
            f16x2 r2 = as_h2((unsigned)qk[k].z), r3 = as_h2((unsigned)qk[k].w);
            f16x2 m0 = a2 * we[0] + (r0 + xr4[0]);
            f16x2 m1 = a2 * we[1] + (r1 + xr4[1]);
            f16x2 m2 = a2 * we[2] + (r2 + xr4[2]);
            f16x2 m3 = a2 * we[3] + (r3 + xr4[3]);
            m0 = pk_leaky(m0, ns); m1 = pk_leaky(m1, ns);
            m2 = pk_leaky(m2, ns); m3 = pk_leaky(m3, ns);
            t[k] = fdot2a(m3, at[3], fdot2a(m2, at[2],
                   fdot2a(m1, at[1], fdot2a(m0, at[0], 0.f))));
        }
        #pragma unroll
        for (int off = 1; off <= 4; off <<= 1) {   // reduce within 8-lane group
            t[0] += __shfl_xor(t[0], off);
            t[1] += __shfl_xor(t[1], off);
            t[2] += __shfl_xor(t[2], off);
            t[3] += __shfl_xor(t[3], off);
        }
        #pragma unroll
        for (int k = 0; k < 4; ++k) {
            float z = vk[k] ? __expf(t[k]) : 0.f;
            S += z;
            f16x2 r0 = as_h2((unsigned)qk[k].x), r1 = as_h2((unsigned)qk[k].y);
            f16x2 r2 = as_h2((unsigned)qk[k].z), r3 = as_h2((unsigned)qk[k].w);
            acc[0] = fmaf(z, (float)r0.x, acc[0]);
            acc[1] = fmaf(z, (float)r0.y, acc[1]);
            acc[2] = fmaf(z, (float)r1.x, acc[2]);
            acc[3] = fmaf(z, (float)r1.y, acc[3]);
            acc[4] = fmaf(z, (float)r2.x, acc[4]);
            acc[5] = fmaf(z, (float)r2.y, acc[5]);
            acc[6] = fmaf(z, (float)r3.x, acc[6]);
            acc[7] = fmaf(z, (float)r3.y, acc[7]);
        }
    }

    if (nv) {
        float4 ba = *(const float4*)(b + fb), bb = *(const float4*)(b + fb + 4);
        float bq[8] = {ba.x, ba.y, ba.z, ba.w, bb.x, bb.y, bb.z, bb.w};
        float inv = 1.f / (S + 1e-16f);
        float h[8];
        #pragma unroll
        for (int j = 0; j < 8; ++j) {
            float v = fmaf(acc[j], inv, bq[j]);
            h[j] = v > 0.f ? v : expm1f(v);
        }
        *(float4*)(out + (size_t)node * D_H + fb)     = make_float4(h[0], h[1], h[2], h[3]);
        *(float4*)(out + (size_t)node * D_H + fb + 4) = make_float4(h[4], h[5], h[6], h[7]);
    }
}

// ---- global mean pool (batch is sorted): register accumulate, flush on change.
// r7 (kept): CHUNK=32 — 4x shorter serial dependent-load chain than 128.
__global__ void pool(const float* __restrict__ h, const int* __restrict__ batch,
                     float* __restrict__ pooled, float* __restrict__ counts) {
    const int CHUNK = 32;
    int base = blockIdx.x * CHUNK;
    int d = threadIdx.x;  // blockDim = 64
    float accv = 0.f; int cur_g = -1; int cnt = 0;
    for (int i = 0; i < CHUNK; ++i) {
        int n = base + i;
        if (n >= N_NODES) break;
        int g = batch[n];
        if (g != cur_g) {
            if (cur_g >= 0) {
                atomicAdd(&pooled[cur_g * D_H + d], accv);
                if (d == 0) atomicAdd(&counts[cur_g], (float)cnt);
            }
            cur_g = g; accv = 0.f; cnt = 0;
        }
        accv += h[(size_t)n * D_H + d];
        cnt++;
    }
    if (cur_g >= 0) {
        atomicAdd(&pooled[cur_g * D_H + d], accv);
        if (d == 0) atomicAdd(&counts[cur_g], (float)cnt);
    }
}

__global__ void classify(const float* __restrict__ pooled, const float* __restrict__ counts,
                         const float* __restrict__ Wc, const float* __restrict__ bc,
                         float* __restrict__ out) {
    int tid = threadIdx.x;             // 640 threads
    int g = tid / N_CLS, c = tid % N_CLS;
    if (g >= N_GRAPHS) return;
    float inv = 1.0f / fmaxf(counts[g], 1.0f);
    float a = bc[c];
    for (int k = 0; k < D_H; ++k)
        a = fmaf(pooled[g * D_H + k] * inv, Wc[k * N_CLS + c], a);
    out[g * N_CLS + c] = a;
}

extern "C" void kernel_launch(void* const* d_in, const int* in_sizes, int n_in,
                              void* d_out, int out_size, void* d_ws, size_t ws_size,
                              hipStream_t stream) {
    const float* x     = (const float*)d_in[0];
    const int*   ei    = (const int*)d_in[1];
    const float* eattr = (const float*)d_in[2];
    const int*   batch = (const int*)d_in[3];
    const float *Wl1 = (const float*)d_in[4],  *bl1 = (const float*)d_in[5];
    const float *Wr1 = (const float*)d_in[6],  *br1 = (const float*)d_in[7];
    const float *We1 = (const float*)d_in[8],  *att1 = (const float*)d_in[9];
    const float *b1  = (const float*)d_in[10];
    const float *Wl2 = (const float*)d_in[11], *bl2 = (const float*)d_in[12];
    const float *Wr2 = (const float*)d_in[13], *br2 = (const float*)d_in[14];
    const float *We2 = (const float*)d_in[15], *att2 = (const float*)d_in[16];
    const float *b2  = (const float*)d_in[17];
    const float *Wc  = (const float*)d_in[18], *bc = (const float*)d_in[19];
    float* out = (float*)d_out;

    const int* src = ei;
    const int* dst = ei + N_EDGES;

    // workspace layout. stg (int2, 15.36 MB) is dead after scatter; xl/xr (fp16,
    // 6.4 MB each) + h (fp32, 12.8 MB) = 25.6 MB alias its region. csr_pack kept
    // at the old 30.72 MB offset so it stays clear of xl/xr/h.
    char* base = (char*)d_ws;
    int2*  stg     = (int2*)base;                       // NB*CAP*8B = 15.36 MB
    __half* xl     = (__half*)base;                     // N*64 fp16 (6.4 MB)
    __half* xr     = xl + (size_t)N_NODES * D_H;        // N*64 fp16
    float* h       = (float*)(xr + (size_t)N_NODES * D_H); // N*64 fp32 (12.8 MB)
    int2*  csr_pack = (int2*)(base + (size_t)NB * CAP * 16); // E2 (8B) = 13.2 MB
    int*   row_start = (int*)(csr_pack + E2);           // N+1
    int*   cnt     = row_start + N_NODES + 1;           // N
    float* esum    = (float*)(cnt + N_NODES);           // 32 lines (32*PAD floats)
    int*   bcursor = (int*)(esum + 32 * PAD);           // NB lines (NB*PAD ints)
    int*   cursor  = bcursor + NB * PAD;                // N
    int*   partial = cursor + N_NODES;                  // NBLK
    float* pooled  = (float*)(partial + NBLK);          // 64*64
    float* counts  = pooled + N_GRAPHS * D_H;           // 64

    int gat_blocks = (N_NODES + 31) / 32;               // 32 nodes per 256-thr block
    int lin_blocks = (N_NODES + 31) / 32;               // 32 nodes per block (TN=32)

    hipMemsetAsync(cnt, 0, (N_NODES + 32 * PAD + NB * PAD) * sizeof(int), stream);
    hipMemsetAsync(pooled, 0, (N_GRAPHS * D_H + N_GRAPHS) * sizeof(float), stream);

    // ---- CSR build: stage -> LDS hist -> scan -> slice-scatter ----
    bucket_stage<<<(N_EDGES / EPT + 255) / 256, 256, 0, stream>>>(
        src, dst, eattr, esum, bcursor, stg);
    hist_bucket<<<NB * HBB, 256, 0, stream>>>(stg, bcursor, cnt);
    scan_block<<<NBLK, SCAN_BS, 0, stream>>>(cnt, row_start, partial);
    add_offsets<<<NBLK, SCAN_BS, 0, stream>>>(row_start, partial, cursor, esum, csr_pack);
    scatter_slice<<<SLICES * 32, 1024, 0, stream>>>(stg, bcursor, row_start, csr_pack);

    // ---------------- layer 1 ----------------
    linear_dual_k<D_IN><<<lin_blocks, 256, 0, stream>>>(x, Wl1, bl1, Wr1, br1, xl, xr);
    gat_fused<<<gat_blocks, 256, 0, stream>>>(row_start, csr_pack, xl, xr, We1, att1, b1, h);

    // ---------------- layer 2 ----------------
    linear_dual_k<D_H><<<lin_blocks, 256, 0, stream>>>(h, Wl2, bl2, Wr2, br2, xl, xr);
    gat_fused<<<gat_blocks, 256, 0, stream>>>(row_start, csr_pack, xl, xr, We2, att2, b2, h);

    // ---------------- pool + classify ----------------
    pool<<<(N_NODES + 31) / 32, 64, 0, stream>>>(h, batch, pooled, counts);
    classify<<<1, 640, 0, stream>>>(pooled, counts, Wc, bc, out);
}